// Round 1
// baseline (540.517 us; speedup 1.0000x reference)
//
#include <hip/hip_runtime.h>
#include <cmath>

#define IMG_H 512
#define IMG_W 512
#define TILE_W 64
#define TILE_H 32
#define LDSW 72   // 64 + 8 halo/alignment cols (covers x0-4 .. x0+67)
#define LDSH 38   // 32 + 6 halo rows (covers y0-3 .. y0+34)
#define NTHREADS 256

struct Coeffs {
  float lpf[9];
  float log3[9];
  float log5[25];
  float log7[49];
  float hpf3[9];
  float hpf5[25];
  float gab[4][49];
};

__device__ __forceinline__ float fast_tanh(float x) {
  // tanh(x) = 1 - 2/(exp2(x*2*log2(e)) + 1); exp overflow -> +/-1 naturally
  float e = __builtin_amdgcn_exp2f(x * 2.8853900817779268f);
  return 1.0f - 2.0f * __builtin_amdgcn_rcpf(e + 1.0f);
}

__device__ __forceinline__ float squash_from(float z) {
  // (tanh(0.1 z)+1)/2
  return fmaf(fast_tanh(0.1f * z), 0.5f, 0.5f);
}

__global__ __launch_bounds__(NTHREADS)
void msif_kernel(const float* __restrict__ x, float* __restrict__ out,
                 int planes, int do_gab, Coeffs C) {
  __shared__ float tile[LDSH * LDSW];
  const int tid = threadIdx.x;
  const int tx = tid & 15;   // 16 threads in x, 4 px each -> 64 wide
  const int ty = tid >> 4;   // 16 threads in y, 2 rows each -> 32 tall
  const int x0 = blockIdx.x * TILE_W;
  const int y0 = blockIdx.y * TILE_H;
  const int plane = blockIdx.z;
  const float* __restrict__ in = x + (size_t)plane * (IMG_H * IMG_W);

  // ---- stage input tile (with zero padding at image borders) ----
  const int gx0 = x0 - 4;
  const int gy0 = y0 - 3;
  for (int k = tid; k < LDSH * (LDSW / 4); k += NTHREADS) {
    int r = k / (LDSW / 4);
    int cc = (k - r * (LDSW / 4)) * 4;
    int gy = gy0 + r;
    int gx = gx0 + cc;
    float4 v = make_float4(0.f, 0.f, 0.f, 0.f);
    if ((unsigned)gy < IMG_H) {
      const float* rowp = in + (size_t)gy * IMG_W;
      if (gx >= 0 && gx + 3 < IMG_W) {
        v = *(const float4*)(rowp + gx);
      } else {
        float t0 = 0.f, t1 = 0.f, t2 = 0.f, t3 = 0.f;
        if ((unsigned)(gx + 0) < IMG_W) t0 = rowp[gx + 0];
        if ((unsigned)(gx + 1) < IMG_W) t1 = rowp[gx + 1];
        if ((unsigned)(gx + 2) < IMG_W) t2 = rowp[gx + 2];
        if ((unsigned)(gx + 3) < IMG_W) t3 = rowp[gx + 3];
        v = make_float4(t0, t1, t2, t3);
      }
    }
    *(float4*)&tile[r * LDSW + cc] = v;
  }
  __syncthreads();

  // ---- accumulate 10 convolutions for 4x2 pixels per thread ----
  float a_lpf[2][4] = {};
  float a_l3[2][4] = {};
  float a_l5[2][4] = {};
  float a_l7[2][4] = {};
  float a_h3[2][4] = {};
  float a_h5[2][4] = {};
  float a_g[4][2][4] = {};

  const int base_row = 2 * ty;

#pragma unroll
  for (int ir = 0; ir < 8; ++ir) {
    const float4* p = (const float4*)&tile[(base_row + ir) * LDSW + 4 * tx];
    float4 w0 = p[0], w1 = p[1], w2 = p[2];
    float w[12] = {w0.x, w0.y, w0.z, w0.w, w1.x, w1.y, w1.z, w1.w,
                   w2.x, w2.y, w2.z, w2.w};
#pragma unroll
    for (int row = 0; row < 2; ++row) {
      const int dr = ir - row;  // 7x7 kernel row index (input row = yo + dr - 3)
      if (dr >= 0 && dr <= 6) {
#pragma unroll
        for (int dx = 0; dx < 7; ++dx) {
          const float c7 = C.log7[dr * 7 + dx];
          const float g0 = C.gab[0][dr * 7 + dx];
          const float g1 = C.gab[1][dr * 7 + dx];
          const float g2 = C.gab[2][dr * 7 + dx];
          const float g3 = C.gab[3][dr * 7 + dx];
#pragma unroll
          for (int c = 0; c < 4; ++c) {
            const float v = w[c + dx + 1];
            a_l7[row][c] = fmaf(v, c7, a_l7[row][c]);
            a_g[0][row][c] = fmaf(v, g0, a_g[0][row][c]);
            a_g[1][row][c] = fmaf(v, g1, a_g[1][row][c]);
            a_g[2][row][c] = fmaf(v, g2, a_g[2][row][c]);
            a_g[3][row][c] = fmaf(v, g3, a_g[3][row][c]);
          }
        }
      }
      if (dr >= 1 && dr <= 5) {
        const int kr = dr - 1;
#pragma unroll
        for (int dx = 0; dx < 5; ++dx) {
          const float c5 = C.log5[kr * 5 + dx];
          const float h5 = C.hpf5[kr * 5 + dx];
#pragma unroll
          for (int c = 0; c < 4; ++c) {
            const float v = w[c + dx + 2];
            a_l5[row][c] = fmaf(v, c5, a_l5[row][c]);
            a_h5[row][c] = fmaf(v, h5, a_h5[row][c]);
          }
        }
      }
      if (dr >= 2 && dr <= 4) {
        const int kr = dr - 2;
#pragma unroll
        for (int dx = 0; dx < 3; ++dx) {
          const float cl = C.lpf[kr * 3 + dx];
          const float c3 = C.log3[kr * 3 + dx];
          const float h3 = C.hpf3[kr * 3 + dx];
#pragma unroll
          for (int c = 0; c < 4; ++c) {
            const float v = w[c + dx + 3];
            a_lpf[row][c] = fmaf(v, cl, a_lpf[row][c]);
            a_l3[row][c] = fmaf(v, c3, a_l3[row][c]);
            a_h3[row][c] = fmaf(v, h3, a_h3[row][c]);
          }
        }
      }
    }
  }

  // ---- epilogue: squash/tanh (max commutes with monotone fns), store ----
  const int X = x0 + 4 * tx;
  const size_t fs = (size_t)planes * (IMG_H * IMG_W);   // per-output stride
  const size_t pbase = (size_t)plane * (IMG_H * IMG_W);

#pragma unroll
  for (int row = 0; row < 2; ++row) {
    const int yo = y0 + base_row + row;
    const size_t off = pbase + (size_t)yo * IMG_W + X;

    float4 orig = *(const float4*)&tile[(base_row + row + 3) * LDSW + 4 * tx + 4];
    *(float4*)(out + off) = orig;

    float lo[4], ho[4], go[4];
#pragma unroll
    for (int c = 0; c < 4; ++c) {
      float lm = fmaxf(fmaxf(a_l3[row][c], a_l5[row][c]), a_l7[row][c]);
      lo[c] = squash_from(lm);
      float hm = fmaxf(a_h3[row][c], a_h5[row][c]);
      ho[c] = squash_from(hm);
      float gm = fmaxf(fmaxf(a_g[0][row][c], a_g[1][row][c]),
                       fmaxf(a_g[2][row][c], a_g[3][row][c]));
      go[c] = fast_tanh(0.1f * gm);
    }
    *(float4*)(out + fs + off) =
        make_float4(a_lpf[row][0], a_lpf[row][1], a_lpf[row][2], a_lpf[row][3]);
    *(float4*)(out + 2 * fs + off) = make_float4(lo[0], lo[1], lo[2], lo[3]);
    *(float4*)(out + 3 * fs + off) = make_float4(ho[0], ho[1], ho[2], ho[3]);
    if (do_gab)
      *(float4*)(out + 4 * fs + off) = make_float4(go[0], go[1], go[2], go[3]);
  }
}

// ---------------- host-side coefficient generation (double, matches numpy) --

static void make_log_k(int ks, double sigma, float* out) {
  double buf[49];
  int h = ks / 2;
  double s = 0.0;
  for (int i = 0; i < ks; ++i) {
    for (int j = 0; j < ks; ++j) {
      double xi = (double)(i - h);  // xx = ax[i] (indexing='ij')
      double yj = (double)(j - h);
      double r2 = xi * xi + yj * yj;
      double g = exp(-r2 / (2.0 * sigma * sigma));
      double lap = -1.0 / (M_PI * sigma * sigma * sigma * sigma) *
                   (1.0 - r2 / (2.0 * sigma * sigma));
      double v = lap * g;
      buf[i * ks + j] = v;
      s += fabs(v);
    }
  }
  for (int k = 0; k < ks * ks; ++k) out[k] = (float)(buf[k] / s);
}

static void make_gabor_k(double angle_deg, float* out) {
  const double freq = 0.1, sx = 2.0, sy = 2.0;
  double th = angle_deg * M_PI / 180.0;
  double ct = cos(th), st = sin(th);
  double buf[49];
  double s = 0.0;
  for (int i = 0; i < 7; ++i) {     // row index -> y (np.meshgrid 'xy')
    for (int j = 0; j < 7; ++j) {   // col index -> x
      double xv = (double)(j - 3);
      double yv = (double)(i - 3);
      double xt = xv * ct + yv * st;
      double yt = -xv * st + yv * ct;
      double g = exp(-(xt * xt / (sx * sx) + yt * yt / (sy * sy)) / 2.0) *
                 cos(2.0 * M_PI * freq * xt);
      buf[i * 7 + j] = g;
      s += fabs(g);
    }
  }
  for (int k = 0; k < 49; ++k) out[k] = (float)(buf[k] / s);
}

extern "C" void kernel_launch(void* const* d_in, const int* in_sizes, int n_in,
                              void* d_out, int out_size, void* d_ws, size_t ws_size,
                              hipStream_t stream) {
  const float* x = (const float*)d_in[0];
  float* out = (float*)d_out;
  const int plane_elems = IMG_H * IMG_W;
  const int planes = in_sizes[0] / plane_elems;                 // 16*3 = 48
  const int do_gab = (out_size >= 5 * in_sizes[0]) ? 1 : 0;

  Coeffs C;
  const float lpf_v[9] = {1.f / 16, 2.f / 16, 1.f / 16, 2.f / 16, 4.f / 16,
                          2.f / 16, 1.f / 16, 2.f / 16, 1.f / 16};
  for (int k = 0; k < 9; ++k) C.lpf[k] = lpf_v[k];
  for (int k = 0; k < 9; ++k) C.hpf3[k] = -1.f;
  C.hpf3[4] = 8.f;
  for (int k = 0; k < 25; ++k) C.hpf5[k] = -1.f;
  C.hpf5[12] = 24.f;
  make_log_k(3, 0.8, C.log3);
  make_log_k(5, 1.0, C.log5);
  make_log_k(7, 1.4, C.log7);
  const double angs[4] = {0.0, 45.0, 90.0, 135.0};
  for (int a = 0; a < 4; ++a) make_gabor_k(angs[a], C.gab[a]);

  dim3 grid(IMG_W / TILE_W, IMG_H / TILE_H, planes);
  msif_kernel<<<grid, NTHREADS, 0, stream>>>(x, out, planes, do_gab, C);
}

// Round 2
// 316.185 us; speedup vs baseline: 1.7095x; 1.7095x over previous
//
#include <hip/hip_runtime.h>

#define IMG_H 512
#define IMG_W 512
#define TILE_W 64
#define TILE_H 16
#define LDSW 72   // 64 + 8 halo/alignment cols (covers x0-4 .. x0+67)
#define LDSH 22   // 16 + 6 halo rows (covers y0-3 .. y0+18)
#define NTHREADS 256

// ---------------- compile-time coefficient generation --------------------
// All filter kernels are input-independent, so we evaluate them at COMPILE
// TIME in double precision (constexpr Taylor exp/cos/sin, |arg|<=4.6,
// accuracy ~1e-13 -> float rounding identical to numpy float64->float32).
// Coefficients become inline literals in the FMA stream: no kernarg struct,
// no SGPR pressure, no dynamic indexing, nothing spillable.

constexpr double PI_D = 3.141592653589793238462643383279502884;

constexpr double cexp(double x) {
  double term = 1.0, sum = 1.0;
  for (int n = 1; n < 48; ++n) { term *= x / n; sum += term; }
  return sum;
}
constexpr double ccos(double x) {
  double term = 1.0, sum = 1.0;
  for (int n = 1; n < 24; ++n) {
    term *= -x * x / ((2.0 * n - 1.0) * (2.0 * n));
    sum += term;
  }
  return sum;
}
constexpr double csin(double x) {
  double term = x, sum = x;
  for (int n = 1; n < 24; ++n) {
    term *= -x * x / ((2.0 * n) * (2.0 * n + 1.0));
    sum += term;
  }
  return sum;
}
constexpr double cabs_(double x) { return x < 0 ? -x : x; }

struct KTabs {
  float lpf[9];
  float log3[9];
  float log5[25];
  float log7[49];
  float hpf3[9];
  float hpf5[25];
  float gab[4][49];
};

constexpr void fill_log(int ks, double sigma, float* out) {
  double buf[49] = {};
  double s = 0.0;
  const int h = ks / 2;
  for (int i = 0; i < ks; ++i) {
    for (int j = 0; j < ks; ++j) {
      const double xi = (double)(i - h);   // meshgrid indexing='ij'
      const double yj = (double)(j - h);
      const double r2 = xi * xi + yj * yj;
      const double g = cexp(-r2 / (2.0 * sigma * sigma));
      const double lap = -1.0 / (PI_D * sigma * sigma * sigma * sigma) *
                         (1.0 - r2 / (2.0 * sigma * sigma));
      buf[i * ks + j] = lap * g;
      s += cabs_(lap * g);
    }
  }
  for (int k = 0; k < ks * ks; ++k) out[k] = (float)(buf[k] / s);
}

constexpr void fill_gabor(double ang_deg, float* out) {
  const double th = ang_deg * PI_D / 180.0;
  const double ct = ccos(th), st = csin(th);
  double buf[49] = {};
  double s = 0.0;
  for (int i = 0; i < 7; ++i) {     // row -> y (np.meshgrid default 'xy')
    for (int j = 0; j < 7; ++j) {   // col -> x
      const double xv = (double)(j - 3);
      const double yv = (double)(i - 3);
      const double xt = xv * ct + yv * st;
      const double yt = -xv * st + yv * ct;
      const double g = cexp(-(xt * xt / 4.0 + yt * yt / 4.0) / 2.0) *
                       ccos(2.0 * PI_D * 0.1 * xt);
      buf[i * 7 + j] = g;
      s += cabs_(g);
    }
  }
  for (int k = 0; k < 49; ++k) out[k] = (float)(buf[k] / s);
}

constexpr KTabs make_tabs() {
  KTabs t{};
  const double lv[9] = {1, 2, 1, 2, 4, 2, 1, 2, 1};
  for (int k = 0; k < 9; ++k) t.lpf[k] = (float)(lv[k] / 16.0);
  for (int k = 0; k < 9; ++k) t.hpf3[k] = -1.0f;
  t.hpf3[4] = 8.0f;
  for (int k = 0; k < 25; ++k) t.hpf5[k] = -1.0f;
  t.hpf5[12] = 24.0f;
  fill_log(3, 0.8, t.log3);
  fill_log(5, 1.0, t.log5);
  fill_log(7, 1.4, t.log7);
  fill_gabor(0.0, t.gab[0]);
  fill_gabor(45.0, t.gab[1]);
  fill_gabor(90.0, t.gab[2]);
  fill_gabor(135.0, t.gab[3]);
  return t;
}

constexpr KTabs KT = make_tabs();

// ------------------------------- kernel ----------------------------------

__device__ __forceinline__ float fast_tanh(float x) {
  // tanh(x) = 1 - 2/(exp2(2x*log2e) + 1); overflow saturates to +/-1
  float e = __builtin_amdgcn_exp2f(x * 2.8853900817779268f);
  return 1.0f - 2.0f * __builtin_amdgcn_rcpf(e + 1.0f);
}
__device__ __forceinline__ float squash_from(float z) {
  return fmaf(fast_tanh(0.1f * z), 0.5f, 0.5f);
}

__global__ __launch_bounds__(NTHREADS)
void msif_kernel(const float* __restrict__ x, float* __restrict__ out,
                 int planes, int do_gab) {
  __shared__ float tile[LDSH * LDSW];
  const int tid = threadIdx.x;
  const int tx = tid & 15;   // 16 threads wide, 4 px each -> 64 cols
  const int ty = tid >> 4;   // 16 rows, 1 px each
  const int x0 = blockIdx.x * TILE_W;
  const int y0 = blockIdx.y * TILE_H;
  const int plane = blockIdx.z;
  const float* __restrict__ in = x + (size_t)plane * (IMG_H * IMG_W);

  // ---- stage input tile (zero padded at borders) ----
  const int gx0 = x0 - 4;
  const int gy0 = y0 - 3;
  for (int k = tid; k < LDSH * (LDSW / 4); k += NTHREADS) {
    int r = k / (LDSW / 4);
    int cc = (k - r * (LDSW / 4)) * 4;
    int gy = gy0 + r;
    int gx = gx0 + cc;
    float4 v = make_float4(0.f, 0.f, 0.f, 0.f);
    if ((unsigned)gy < IMG_H) {
      const float* rowp = in + (size_t)gy * IMG_W;
      if (gx >= 0 && gx + 3 < IMG_W) {
        v = *(const float4*)(rowp + gx);
      } else {
        float t0 = 0.f, t1 = 0.f, t2 = 0.f, t3 = 0.f;
        if ((unsigned)(gx + 0) < IMG_W) t0 = rowp[gx + 0];
        if ((unsigned)(gx + 1) < IMG_W) t1 = rowp[gx + 1];
        if ((unsigned)(gx + 2) < IMG_W) t2 = rowp[gx + 2];
        if ((unsigned)(gx + 3) < IMG_W) t3 = rowp[gx + 3];
        v = make_float4(t0, t1, t2, t3);
      }
    }
    *(float4*)&tile[r * LDSW + cc] = v;
  }
  __syncthreads();

  // ---- 10 depthwise convs, 4 px per thread, coefficients are literals ----
  float l7[4] = {}, l5[4] = {}, l3[4] = {};
  float h5[4] = {}, h3[4] = {}, lp[4] = {};
  float g0[4] = {}, g1[4] = {}, g2[4] = {}, g3[4] = {};

#pragma unroll
  for (int ir = 0; ir < 7; ++ir) {
    const float4* p = (const float4*)&tile[(ty + ir) * LDSW + 4 * tx];
    float4 w0 = p[0], w1 = p[1], w2 = p[2];
    float w[12] = {w0.x, w0.y, w0.z, w0.w, w1.x, w1.y, w1.z, w1.w,
                   w2.x, w2.y, w2.z, w2.w};

#pragma unroll
    for (int dx = 0; dx < 7; ++dx) {
      const float c7 = KT.log7[ir * 7 + dx];
      const float cg0 = KT.gab[0][ir * 7 + dx];
      const float cg1 = KT.gab[1][ir * 7 + dx];
      const float cg2 = KT.gab[2][ir * 7 + dx];
      const float cg3 = KT.gab[3][ir * 7 + dx];
#pragma unroll
      for (int c = 0; c < 4; ++c) {
        const float v = w[c + dx + 1];
        l7[c] = fmaf(v, c7, l7[c]);
        g0[c] = fmaf(v, cg0, g0[c]);
        g1[c] = fmaf(v, cg1, g1[c]);
        g2[c] = fmaf(v, cg2, g2[c]);
        g3[c] = fmaf(v, cg3, g3[c]);
      }
    }
    if (ir >= 1 && ir <= 5) {
      const int kr = ir - 1;
#pragma unroll
      for (int dx = 0; dx < 5; ++dx) {
        const float c5 = KT.log5[kr * 5 + dx];
        const float ch5 = KT.hpf5[kr * 5 + dx];
#pragma unroll
        for (int c = 0; c < 4; ++c) {
          const float v = w[c + dx + 2];
          l5[c] = fmaf(v, c5, l5[c]);
          h5[c] = fmaf(v, ch5, h5[c]);
        }
      }
    }
    if (ir >= 2 && ir <= 4) {
      const int kr = ir - 2;
#pragma unroll
      for (int dx = 0; dx < 3; ++dx) {
        const float cl = KT.lpf[kr * 3 + dx];
        const float c3 = KT.log3[kr * 3 + dx];
        const float ch3 = KT.hpf3[kr * 3 + dx];
#pragma unroll
        for (int c = 0; c < 4; ++c) {
          const float v = w[c + dx + 3];
          lp[c] = fmaf(v, cl, lp[c]);
          l3[c] = fmaf(v, c3, l3[c]);
          h3[c] = fmaf(v, ch3, h3[c]);
        }
      }
    }
  }

  // ---- epilogue: max commutes with monotone tanh/squash; store ----
  const int X = x0 + 4 * tx;
  const int yo = y0 + ty;
  const size_t fs = (size_t)planes * (IMG_H * IMG_W);
  const size_t off = (size_t)plane * (IMG_H * IMG_W) + (size_t)yo * IMG_W + X;

  float4 orig = *(const float4*)&tile[(ty + 3) * LDSW + 4 * tx + 4];
  *(float4*)(out + off) = orig;

  float lo[4], ho[4], go[4];
#pragma unroll
  for (int c = 0; c < 4; ++c) {
    lo[c] = squash_from(fmaxf(fmaxf(l3[c], l5[c]), l7[c]));
    ho[c] = squash_from(fmaxf(h3[c], h5[c]));
    go[c] = fast_tanh(0.1f * fmaxf(fmaxf(g0[c], g1[c]), fmaxf(g2[c], g3[c])));
  }
  *(float4*)(out + fs + off) = make_float4(lp[0], lp[1], lp[2], lp[3]);
  *(float4*)(out + 2 * fs + off) = make_float4(lo[0], lo[1], lo[2], lo[3]);
  *(float4*)(out + 3 * fs + off) = make_float4(ho[0], ho[1], ho[2], ho[3]);
  if (do_gab)
    *(float4*)(out + 4 * fs + off) = make_float4(go[0], go[1], go[2], go[3]);
}

extern "C" void kernel_launch(void* const* d_in, const int* in_sizes, int n_in,
                              void* d_out, int out_size, void* d_ws, size_t ws_size,
                              hipStream_t stream) {
  const float* x = (const float*)d_in[0];
  float* out = (float*)d_out;
  const int plane_elems = IMG_H * IMG_W;
  const int planes = in_sizes[0] / plane_elems;               // 16*3 = 48
  const int do_gab = (out_size >= 5 * in_sizes[0]) ? 1 : 0;

  dim3 grid(IMG_W / TILE_W, IMG_H / TILE_H, planes);
  msif_kernel<<<grid, NTHREADS, 0, stream>>>(x, out, planes, do_gab);
}